// Round 1
// 521.687 us; speedup vs baseline: 1.1687x; 1.1687x over previous
//
#include <hip/hip_runtime.h>

// Shapes (fixed by the reference): B=4, S=2048 -> M=8192; D_IN=K=4096; D_OUT=N=4096; R=16
constexpr int M = 8192;
constexpr int N = 4096;
constexpr int K = 4096;
constexpr float SCALING = 2.0f; // 32/16

typedef __bf16 bf16x8 __attribute__((ext_vector_type(8)));
typedef __bf16 bf16x4 __attribute__((ext_vector_type(4)));
typedef float  f32x4  __attribute__((ext_vector_type(4)));

// ---------------------------------------------------------------------------
// Kernel 1: cast x (fp32) -> bf16, 8 elements / thread (unchanged)
// ---------------------------------------------------------------------------
__global__ __launch_bounds__(256) void qlora_cast_x(const float* __restrict__ x,
                                                    __bf16* __restrict__ xb) {
    const size_t i = ((size_t)blockIdx.x * 256 + threadIdx.x) * 8;
    const float4 v0 = *(const float4*)(x + i);
    const float4 v1 = *(const float4*)(x + i + 4);
    bf16x8 o;
    o[0] = (__bf16)v0.x; o[1] = (__bf16)v0.y; o[2] = (__bf16)v0.z; o[3] = (__bf16)v0.w;
    o[4] = (__bf16)v1.x; o[5] = (__bf16)v1.y; o[6] = (__bf16)v1.z; o[7] = (__bf16)v1.w;
    *(bf16x8*)(xb + i) = o;
}

// ---------------------------------------------------------------------------
// Kernel 2: W_eff[o,i] = w_int[o,i]*scale + 2 * sum_r loraB[o,r]*loraA[r,i]
// REWRITE: o-tile=16 per block (256 blocks), lora_A staged in LDS per
// 16x1024 k-chunk.  Old version: 4096 blocks each streaming all 256 KB of
// lora_A => ~1 GiB of cache traffic.  New: 256 * 256 KB = 16 MB global reads
// of lora_A; kernel is wint-stream bound (~96 MB HBM => ~20 us).
// Row pad 1024->1028 floats: bank = 4*(r+k4) % 32 -> conflict-free.
// ---------------------------------------------------------------------------
__global__ __launch_bounds__(256) void qlora_prep_w(const int* __restrict__ wi,
                                                    const float* __restrict__ wscale,
                                                    const float* __restrict__ lA,
                                                    const float* __restrict__ lB,
                                                    __bf16* __restrict__ W) {
    __shared__ __align__(16) float As[16][1028];
    const int t  = threadIdx.x;
    const int ol = t >> 4;                 // 0..15 (o within tile)
    const int kk = t & 15;                 // 0..15 (k4 phase)
    const int o  = blockIdx.x * 16 + ol;
    const float s = wscale[0];
    float b[16];
#pragma unroll
    for (int r = 0; r < 16; ++r) b[r] = lB[o * 16 + r];

    for (int c = 0; c < 4; ++c) {
        const int c0 = c * 1024;
        // cooperative load of lora_A[0:16][c0:c0+1024] (coalesced float4)
#pragma unroll
        for (int i = 0; i < 16; ++i) {
            const int idx = t + i * 256;   // 0..4095 float4-index
            const int r   = idx >> 8;      // 0..15
            const int c4  = idx & 255;     // 0..255
            const float4 v = *(const float4*)(lA + r * K + c0 + c4 * 4);
            *(float4*)(&As[r][c4 * 4]) = v;
        }
        __syncthreads();
#pragma unroll
        for (int j = 0; j < 16; ++j) {
            const int k4 = kk + j * 16;    // 0..255, coalesced across 16-thread group
            const int kg = c0 + k4 * 4;
            const int4 w4 = *(const int4*)(wi + (size_t)o * K + kg);
            float a0 = 0.f, a1 = 0.f, a2 = 0.f, a3 = 0.f;
#pragma unroll
            for (int r = 0; r < 16; ++r) {
                const float4 a4 = *(const float4*)(&As[r][k4 * 4]);
                a0 += b[r] * a4.x; a1 += b[r] * a4.y;
                a2 += b[r] * a4.z; a3 += b[r] * a4.w;
            }
            bf16x4 v;
            v[0] = (__bf16)((float)w4.x * s + SCALING * a0);
            v[1] = (__bf16)((float)w4.y * s + SCALING * a1);
            v[2] = (__bf16)((float)w4.z * s + SCALING * a2);
            v[3] = (__bf16)((float)w4.w * s + SCALING * a3);
            *(bf16x4*)(W + (size_t)o * K + kg) = v;
        }
        __syncthreads();
    }
}

// ---------------------------------------------------------------------------
// Kernel 3: C[M,N] = Xbf[M,K] @ Wbf[N,K]^T
// 256x256 tile, BK=64, 8 waves (2Mx4N), 128 KiB LDS double-buffer.
// 4-phase schedule per K-tile (16 MFMA per phase, raw s_barrier, setprio):
//   P1: ds_read a[0-3]+b[0-1] (12) | issue ALL 8 stage loads for t+1 | MFMA Q00
//   P2: ds_read b[2-3]        (4)                                    | MFMA Q01
//   P3: ds_read a[4-7]        (8)  (reuses af regs)                  | MFMA Q10
//   P4:                                              MFMA Q11 | vmcnt(0)+bar
// Loads issued at P1 of tile t land in buf[(t+1)&1] (consumed last at t-1,
// all readers past the t-1 boundary barrier -> race-free).  vmcnt(0) sits
// ~3 phases (~1900 cyc) after issue, so it is a no-op stall in steady state
// (T4's mechanism without needing a 3rd LDS buffer).
// LDS swizzle: 16B chunk c of row r stored at slot c ^ (r&7); read slot
// (ks*4+quad) ^ (lb&7)  -> 0 bank conflicts (measured on previous kernel).
// Staging: async16 covers 8 rows x 8 slots; lane l -> row l>>3, slot l&7,
// fetching global chunk (l&7)^(l>>3).  LDS dest = uniform base + lane*16.
// ---------------------------------------------------------------------------
__device__ __forceinline__ void async16(const __bf16* g, __bf16* l) {
    __builtin_amdgcn_global_load_lds(
        (const __attribute__((address_space(1))) unsigned int*)(unsigned long long)g,
        (__attribute__((address_space(3))) unsigned int*)(unsigned int)(unsigned long long)l,
        16, 0, 0);
}

__global__ __launch_bounds__(512, 2) void qlora_gemm_bt(const __bf16* __restrict__ A,
                                                        const __bf16* __restrict__ B,
                                                        float* __restrict__ C) {
    __shared__ __align__(16) __bf16 Lds[65536];   // [2 buf][A 16384 | B 16384] = 128 KiB

    const int tid  = threadIdx.x;
    const int w    = tid >> 6;       // wave 0..7
    const int lane = tid & 63;
    const int quad = lane >> 4;      // 0..3
    const int lb   = lane & 15;
    const int wm   = w >> 2;         // 0..1
    const int wn   = w & 3;          // 0..3

    // XCD-aware bijective swizzle: 512 blocks = 8 XCDs x 64; within an XCD
    // chunk ids run by-fast so 32 concurrent blocks share one B panel in L2.
    const int swz = (blockIdx.x & 7) * 64 + (blockIdx.x >> 3);
    const int bx  = swz >> 5;        // 0..15
    const int by  = swz & 31;        // 0..31
    const size_t mBase = (size_t)by * 256;
    const size_t nBase = (size_t)bx * 256;

    // ---- staging setup: wave w stages rows [w*32, w*32+32) of A and B ----
    const int r8 = lane >> 3;                  // 0..7
    const int ch = ((lane & 7) ^ r8) * 8;      // swizzled global k-chunk (elems)
    const __bf16* gA = A + (mBase + w * 32 + r8) * K + ch;
    const __bf16* gB = B + (nBase + w * 32 + r8) * K + ch;
    __bf16* lA0 = Lds + w * 2048;              // + buf*32768
    __bf16* lB0 = Lds + 16384 + w * 2048;

    // ---- ds_read setup ----
    const int roA = (wm * 128 + lb) * 64;      // row base (elems)
    const int roB = (wn * 64 + lb) * 64;
    const int sw0 = ((0 + quad) ^ (lb & 7)) * 8;   // ks=0 slot (elems)
    const int sw1 = ((4 + quad) ^ (lb & 7)) * 8;   // ks=1 slot

    f32x4 acc[8][4] = {};

    auto stage = [&](int t) {
        const int b = t & 1;
        const size_t kt = (size_t)t * 64;
        const __bf16* pa = gA + kt;
        const __bf16* pb = gB + kt;
        __bf16* la = lA0 + b * 32768;
        __bf16* lbp = lB0 + b * 32768;
#pragma unroll
        for (int j = 0; j < 4; ++j) {
            async16(pa + (size_t)(j * 8) * K, la + j * 512);
            async16(pb + (size_t)(j * 8) * K, lbp + j * 512);
        }
    };

    auto MF = [](bf16x8 a, bf16x8 b, f32x4 c) {
        return __builtin_amdgcn_mfma_f32_16x16x32_bf16(a, b, c, 0, 0, 0);
    };

    stage(0);
    asm volatile("s_waitcnt vmcnt(0)" ::: "memory");
    __builtin_amdgcn_s_barrier();

#pragma unroll 2
    for (int t = 0; t < 64; ++t) {
        const __bf16* Ab = Lds + (t & 1) * 32768;
        const __bf16* Bb = Ab + 16384;

        bf16x8 af[4][2], b01[2][2], b23[2][2];

        // ---------------- P1: reads a[0-3], b[0-1]; issue stage(t+1) -------
#pragma unroll
        for (int fm = 0; fm < 4; ++fm) {
            af[fm][0] = *(const bf16x8*)(Ab + roA + fm * 1024 + sw0);
            af[fm][1] = *(const bf16x8*)(Ab + roA + fm * 1024 + sw1);
        }
#pragma unroll
        for (int fn = 0; fn < 2; ++fn) {
            b01[fn][0] = *(const bf16x8*)(Bb + roB + fn * 1024 + sw0);
            b01[fn][1] = *(const bf16x8*)(Bb + roB + fn * 1024 + sw1);
        }
        if (t + 1 < 64) stage(t + 1);
        __builtin_amdgcn_s_barrier();
        asm volatile("s_waitcnt lgkmcnt(0)" ::: "memory");
        __builtin_amdgcn_s_setprio(1);
#pragma unroll
        for (int fm = 0; fm < 4; ++fm)
#pragma unroll
            for (int fn = 0; fn < 2; ++fn) {
                acc[fm][fn] = MF(af[fm][0], b01[fn][0], acc[fm][fn]);
                acc[fm][fn] = MF(af[fm][1], b01[fn][1], acc[fm][fn]);
            }
        __builtin_amdgcn_s_setprio(0);
        __builtin_amdgcn_s_barrier();

        // ---------------- P2: reads b[2-3]; MFMA Q(0,1) --------------------
#pragma unroll
        for (int fn = 0; fn < 2; ++fn) {
            b23[fn][0] = *(const bf16x8*)(Bb + roB + (fn + 2) * 1024 + sw0);
            b23[fn][1] = *(const bf16x8*)(Bb + roB + (fn + 2) * 1024 + sw1);
        }
        __builtin_amdgcn_s_barrier();
        asm volatile("s_waitcnt lgkmcnt(0)" ::: "memory");
        __builtin_amdgcn_s_setprio(1);
#pragma unroll
        for (int fm = 0; fm < 4; ++fm)
#pragma unroll
            for (int fn = 0; fn < 2; ++fn) {
                acc[fm][fn + 2] = MF(af[fm][0], b23[fn][0], acc[fm][fn + 2]);
                acc[fm][fn + 2] = MF(af[fm][1], b23[fn][1], acc[fm][fn + 2]);
            }
        __builtin_amdgcn_s_setprio(0);
        __builtin_amdgcn_s_barrier();

        // ---------------- P3: reads a[4-7] (reuse af); MFMA Q(1,0) ---------
#pragma unroll
        for (int fm = 0; fm < 4; ++fm) {
            af[fm][0] = *(const bf16x8*)(Ab + roA + (fm + 4) * 1024 + sw0);
            af[fm][1] = *(const bf16x8*)(Ab + roA + (fm + 4) * 1024 + sw1);
        }
        __builtin_amdgcn_s_barrier();
        asm volatile("s_waitcnt lgkmcnt(0)" ::: "memory");
        __builtin_amdgcn_s_setprio(1);
#pragma unroll
        for (int fm = 0; fm < 4; ++fm)
#pragma unroll
            for (int fn = 0; fn < 2; ++fn) {
                acc[fm + 4][fn] = MF(af[fm][0], b01[fn][0], acc[fm + 4][fn]);
                acc[fm + 4][fn] = MF(af[fm][1], b01[fn][1], acc[fm + 4][fn]);
            }
        __builtin_amdgcn_s_setprio(0);
        __builtin_amdgcn_s_barrier();

        // ---------------- P4: MFMA Q(1,1); tile-boundary sync --------------
        __builtin_amdgcn_s_setprio(1);
#pragma unroll
        for (int fm = 0; fm < 4; ++fm)
#pragma unroll
            for (int fn = 0; fn < 2; ++fn) {
                acc[fm + 4][fn + 2] = MF(af[fm][0], b23[fn][0], acc[fm + 4][fn + 2]);
                acc[fm + 4][fn + 2] = MF(af[fm][1], b23[fn][1], acc[fm + 4][fn + 2]);
            }
        __builtin_amdgcn_s_setprio(0);
        asm volatile("s_waitcnt vmcnt(0)" ::: "memory");
        __builtin_amdgcn_s_barrier();
    }

    // Epilogue: D layout col = lane&15, row = quad*4 + reg
#pragma unroll
    for (int fm = 0; fm < 8; ++fm) {
        const size_t m0 = mBase + wm * 128 + fm * 16 + quad * 4;
#pragma unroll
        for (int fn = 0; fn < 4; ++fn) {
            const size_t n0 = nBase + wn * 64 + fn * 16 + lb;
            float* p = C + m0 * N + n0;
            p[0 * (size_t)N] = acc[fm][fn][0];
            p[1 * (size_t)N] = acc[fm][fn][1];
            p[2 * (size_t)N] = acc[fm][fn][2];
            p[3 * (size_t)N] = acc[fm][fn][3];
        }
    }
}

// ---------------------------------------------------------------------------
extern "C" void kernel_launch(void* const* d_in, const int* in_sizes, int n_in,
                              void* d_out, int out_size, void* d_ws, size_t ws_size,
                              hipStream_t stream) {
    const float* x      = (const float*)d_in[0];
    const int*   wint   = (const int*)d_in[1];
    const float* wscale = (const float*)d_in[2];
    const float* lA     = (const float*)d_in[3];
    const float* lB     = (const float*)d_in[4];
    float* out = (float*)d_out;

    __bf16* Xb = (__bf16*)d_ws;                                   // M*K*2 = 64 MiB
    __bf16* Wb = (__bf16*)((char*)d_ws + (size_t)M * K * 2);      // N*K*2 = 32 MiB

    qlora_cast_x<<<16384, 256, 0, stream>>>(x, Xb);
    qlora_prep_w<<<256, 256, 0, stream>>>(wint, wscale, lA, lB, Wb);
    qlora_gemm_bt<<<dim3(512), dim3(512), 0, stream>>>(Xb, Wb, out);
}